// Round 4
// baseline (457.779 us; speedup 1.0000x reference)
//
#include <hip/hip_runtime.h>
#include <hip/hip_bf16.h>

#define TD 128    // feature dim, fixed by problem
#define WS 136    // padded W-LDS row stride in bf16 (272 B: 16B-aligned, bank-uniform for b128)
#define SC_T 16   // triples per scoring block (R4: 8->16 halves W-stage traffic)
#define BKT_SH 7  // 128 nodes per CSR bucket (NB = ceil(N/128) <= 1024 for N <= 131072)
#define NBLK 256  // partition blocks for hist/scat passes

typedef __attribute__((ext_vector_type(8))) short bf16x8;   // 8 bf16 = 4 VGPR (MFMA A/B frag)
typedef __attribute__((ext_vector_type(4))) float f32x4;    // MFMA C/D frag

static __device__ __forceinline__ unsigned short f2bf(float f) {
    unsigned int u = __float_as_uint(f);
    u += 0x7fffu + ((u >> 16) & 1u);   // round-to-nearest-even
    return (unsigned short)(u >> 16);
}
static __device__ __forceinline__ float bf2f(unsigned short h) {
    return __uint_as_float((unsigned int)h << 16);
}

// ================= atomic-free CSR build =================
// R3: global atomic RMWs hit a ~24 op/ns chip floor with ~32B/op HBM write-through; replaced
// by LDS-histogram multi-split (zero global atomics). R4: k_rcnt folded in here (2nd LDS histo).

// pass 1: per-block bucket histogram (+ relation histogram for scoring bucketing).
__global__ __launch_bounds__(256) void kc_hist(const int* __restrict__ ei, int* __restrict__ bh,
                                               const int* __restrict__ rel, int* __restrict__ rcount,
                                               int E_, int ES_, int NB, int chunk, int rchunk) {
    __shared__ int lh[1024];
    __shared__ int rh[16];
    int t = threadIdx.x, blk = blockIdx.x;
    for (int j = t; j < NB; j += 256) lh[j] = 0;
    if (t < 16) rh[t] = 0;
    __syncthreads();
    int e0 = blk * chunk, e1 = min(E_, e0 + chunk);
    for (int e = e0 + t; e < e1; e += 256)
        atomicAdd(&lh[ei[E_ + e] >> BKT_SH], 1);   // LDS atomic
    int r0 = blk * rchunk, r1 = min(ES_, r0 + rchunk);
    for (int e = r0 + t; e < r1; e += 256)
        atomicAdd(&rh[rel[e]], 1);                 // LDS atomic
    __syncthreads();
    for (int j = t; j < NB; j += 256) bh[(size_t)j * NBLK + blk] = lh[j];
    if (t < 16 && rh[t]) atomicAdd(&rcount[t], rh[t]);   // fire-and-forget, 16/block
}

// pass 2a: per bucket, exclusive scan over the NBLK block counts (in place); tot[b] = bucket size
__global__ __launch_bounds__(64) void kc_scanA(int* __restrict__ bh, int* __restrict__ tot, int NB) {
    int b = blockIdx.x, l = threadIdx.x;
    int* row = bh + (size_t)b * NBLK;
    int run = 0;
#pragma unroll
    for (int g = 0; g < NBLK / 64; ++g) {
        int v = row[g * 64 + l];
        int x = v;
#pragma unroll
        for (int off = 1; off < 64; off <<= 1) {
            int y = __shfl_up(x, off);
            if (l >= off) x += y;
        }
        row[g * 64 + l] = run + x - v;   // exclusive within bucket
        run += __shfl(x, 63);
    }
    if (l == 0) tot[b] = run;
}

// pass 2b: single-block exclusive scan of bucket totals -> boff[0..NB], rowptr[N] = E
__global__ __launch_bounds__(256) void kc_scanB(const int* __restrict__ tot, int* __restrict__ boff,
                                                int NB, int* __restrict__ rowptrN) {
    __shared__ int wsum[4];
    int t = threadIdx.x;
    int base = t * 4;
    int a0 = (base     < NB) ? tot[base]     : 0;
    int a1 = (base + 1 < NB) ? tot[base + 1] : 0;
    int a2 = (base + 2 < NB) ? tot[base + 2] : 0;
    int a3 = (base + 3 < NB) ? tot[base + 3] : 0;
    int s1 = a0 + a1, s2 = s1 + a2, tt = s2 + a3;
    int lane = t & 63, wv = t >> 6;
    int x = tt;
#pragma unroll
    for (int off = 1; off < 64; off <<= 1) {
        int y = __shfl_up(x, off);
        if (lane >= off) x += y;
    }
    if (lane == 63) wsum[wv] = x;
    __syncthreads();
    int woff = 0;
    for (int w = 0; w < wv; ++w) woff += wsum[w];
    int excl = woff + x - tt;
    if (base     < NB) boff[base]     = excl;
    if (base + 1 < NB) boff[base + 1] = excl + a0;
    if (base + 2 < NB) boff[base + 2] = excl + s1;
    if (base + 3 < NB) boff[base + 3] = excl + s2;
    if (t == 255) { boff[NB] = woff + x; *rowptrN = woff + x; }
}

// pass 3: scatter edges into bucket-grouped ebuf, packed (src<<7)|(dst&127). LDS-atomic ranks.
__global__ __launch_bounds__(256) void kc_scat(const int* __restrict__ ei, const int* __restrict__ bh,
                                               const int* __restrict__ boff, int* __restrict__ ebuf,
                                               int E_, int NB, int chunk) {
    __shared__ int lh[1024];
    int t = threadIdx.x, blk = blockIdx.x;
    for (int j = t; j < NB; j += 256) lh[j] = 0;
    __syncthreads();
    int e0 = blk * chunk, e1 = min(E_, e0 + chunk);
    for (int e = e0 + t; e < e1; e += 256) {
        int s = ei[e];
        int d = ei[E_ + e];
        int b = d >> BKT_SH;
        int lr = atomicAdd(&lh[b], 1);   // LDS atomic: rank within (block, bucket)
        int slot = boff[b] + bh[(size_t)b * NBLK + blk] + lr;
        ebuf[slot] = (s << BKT_SH) | (d & ((1 << BKT_SH) - 1));
    }
}

// pass 4: one block per bucket -> exact per-node counting sort. Writes rowptr, dinv, esrc.
__global__ __launch_bounds__(256) void kc_build(const int* __restrict__ ebuf, const int* __restrict__ boff,
                                                int* __restrict__ rowptr, float* __restrict__ dinv,
                                                int* __restrict__ esrc, int n) {
    __shared__ int hist[128], excl[128], cur[128];
    __shared__ int w0;
    int b = blockIdx.x, t = threadIdx.x;
    int node0 = b << BKT_SH;
    int s = boff[b], e = boff[b + 1];
    if (t < 128) { hist[t] = 0; cur[t] = 0; }
    __syncthreads();
    for (int i = s + t; i < e; i += 256)
        atomicAdd(&hist[ebuf[i] & 127], 1);   // LDS atomic
    __syncthreads();
    // scan the 128 counts (waves 0,1 active; uniform syncs)
    int v = (t < 128) ? hist[t] : 0;
    int lane = t & 63, wv = t >> 6;
    int x = v;
#pragma unroll
    for (int off = 1; off < 64; off <<= 1) {
        int y = __shfl_up(x, off);
        if (lane >= off) x += y;
    }
    if (t == 63) w0 = x;
    __syncthreads();
    if (t < 128) {
        int ex = x - v + (wv == 1 ? w0 : 0);
        excl[t] = ex;
        int node = node0 + t;
        if (node < n) {
            rowptr[node] = s + ex;
            dinv[node] = (v > 0) ? 1.0f / sqrtf((float)v) : 0.0f;
        }
    }
    __syncthreads();
    for (int i = s + t; i < e; i += 256) {
        int p = ebuf[i];
        int loc = p & 127;
        int lr = atomicAdd(&cur[loc], 1);   // LDS atomic
        esrc[s + excl[loc] + lr] = p >> BKT_SH;
    }
}

// ---------------- W transpose + hi/lo bf16 split ----------------
__global__ __launch_bounds__(256) void k_wsplit(const float* __restrict__ W1, const float* __restrict__ W2,
                                                unsigned short* __restrict__ Wt) {
    int i = blockIdx.x * 256 + threadIdx.x;   // 0 .. 2*16384-1
    int w = i >> 14;
    int idx = i & 16383;          // = k*128 + n  (coalesced read)
    int k = idx >> 7, n = idx & 127;
    float x = (w ? W2 : W1)[idx];
    unsigned short h = f2bf(x);
    unsigned short l = f2bf(x - bf2f(h));
    size_t base = (size_t)w * 32768;
    Wt[base + n * 128 + k] = h;
    Wt[base + 16384 + n * 128 + k] = l;
}

// ---------------- MFMA GEMM v6: persistent W, grid-stride tiles ----------------
// R4: v5 staged 128KB of W per block (1563 blocks = 200MB L2 reads + a barrier per 64 rows,
// ~3 stage rounds at 2 blocks/CU). v6: grid = 512 (exactly 2/CU), W staged ONCE per block,
// then barrier-free grid-stride loop over 64-row tiles: load A -> convert hi/lo -> 96 MFMA
// from LDS -> direct bf16 stores. Stage traffic /3, one __syncthreads total per block.
__global__ __launch_bounds__(256, 2) void k_gemm(const float* __restrict__ X,
                                                 const unsigned short* __restrict__ Wth,
                                                 const unsigned short* __restrict__ Wtl,
                                                 const float* __restrict__ scale,
                                                 unsigned short* __restrict__ out,
                                                 int nrows, int ntiles) {
    __shared__ __align__(16) unsigned short Wl[2][128 * WS];   // 68 KB (hi, lo)
    const int t = threadIdx.x;
    const int w = t >> 6;
    const int lane = t & 63;
    const int l15 = lane & 15;
    const int quad = lane >> 4;

    // stage W hi+lo -> padded LDS: 2048 uint4 per plane, 8 per thread (once per block)
    {
        const uint4* gh = (const uint4*)Wth;
        const uint4* gl = (const uint4*)Wtl;
#pragma unroll
        for (int it = 0; it < 8; ++it) {
            int idx = t + it * 256;            // 0..2047
            int n = idx >> 4, kg = idx & 15;   // row n, k-group kg (8 bf16 each)
            uint4 vh = gh[idx];
            uint4 vl = gl[idx];
            *(uint4*)&Wl[0][n * WS + kg * 8] = vh;
            *(uint4*)&Wl[1][n * WS + kg * 8] = vl;
        }
    }
    __syncthreads();   // W resident for the rest of the kernel

    for (int tile = blockIdx.x; tile < ntiles; tile += gridDim.x) {
        const int rbase = tile * 64 + w * 16;   // wave's 16-row tile
        const int arow = rbase + l15;           // this lane's A row
        const bool avalid = arow < nrows;

        float4 xa[4][2];
#pragma unroll
        for (int kc = 0; kc < 4; ++kc) {
            const float* src = X + (size_t)arow * TD + kc * 32 + quad * 8;
            xa[kc][0] = avalid ? *(const float4*)src       : make_float4(0.f, 0.f, 0.f, 0.f);
            xa[kc][1] = avalid ? *(const float4*)(src + 4) : make_float4(0.f, 0.f, 0.f, 0.f);
        }
        bf16x8 ah[4], al[4];
#pragma unroll
        for (int kc = 0; kc < 4; ++kc) {
#pragma unroll
            for (int j = 0; j < 8; ++j) {
                float v = (j < 4) ? ((const float*)&xa[kc][0])[j] : ((const float*)&xa[kc][1])[j - 4];
                unsigned short h = f2bf(v);
                ah[kc][j] = (short)h;
                al[kc][j] = (short)f2bf(v - bf2f(h));
            }
        }

        f32x4 acc[8];
#pragma unroll
        for (int b = 0; b < 8; ++b) acc[b] = (f32x4){0.f, 0.f, 0.f, 0.f};
#pragma unroll
        for (int kc = 0; kc < 4; ++kc) {
            const int koff = kc * 32 + quad * 8;
#pragma unroll
            for (int b = 0; b < 8; ++b) {
                const int boff = (b * 16 + l15) * WS + koff;
                bf16x8 bh = *(const bf16x8*)&Wl[0][boff];
                bf16x8 bl = *(const bf16x8*)&Wl[1][boff];
                acc[b] = __builtin_amdgcn_mfma_f32_16x16x32_bf16(ah[kc], bh, acc[b], 0, 0, 0);
                acc[b] = __builtin_amdgcn_mfma_f32_16x16x32_bf16(al[kc], bh, acc[b], 0, 0, 0);
                acc[b] = __builtin_amdgcn_mfma_f32_16x16x32_bf16(ah[kc], bl, acc[b], 0, 0, 0);
            }
        }

        // epilogue: C/D layout col=lane&15, row=quad*4+reg -> scale + direct bf16 global stores
        int grow = rbase + quad * 4;              // multiple of 4; nrows % 4 == 0
        if (grow < nrows) {
            float4 s4 = *(const float4*)&scale[grow];
#pragma unroll
            for (int b = 0; b < 8; ++b) {
                int col = b * 16 + l15;
                out[(size_t)(grow + 0) * TD + col] = f2bf(acc[b][0] * s4.x);
                out[(size_t)(grow + 1) * TD + col] = f2bf(acc[b][1] * s4.y);
                out[(size_t)(grow + 2) * TD + col] = f2bf(acc[b][2] * s4.z);
                out[(size_t)(grow + 3) * TD + col] = f2bf(acc[b][3] * s4.w);
            }
        }
    }
}

// ---------------- CSR aggregation: bf16 gather, f32 accumulate, 4-edge unrolled ----------------
// R3 counters: 230MB L2-miss traffic in 63us = 3.65 TB/s = the random-256B-gather pattern
// ceiling (compulsory per-XCD misses: 25.6MB bufA x 8 XCDs; random 64B/channel DRAM access).
// VALUBusy 27%. At bf16 this kernel is at its roofline; left byte-identical.
#define ACC8(p, u) \
    p##0 += __uint_as_float(u.x << 16); p##1 += __uint_as_float(u.x & 0xffff0000u); \
    p##2 += __uint_as_float(u.y << 16); p##3 += __uint_as_float(u.y & 0xffff0000u); \
    p##4 += __uint_as_float(u.z << 16); p##5 += __uint_as_float(u.z & 0xffff0000u); \
    p##6 += __uint_as_float(u.w << 16); p##7 += __uint_as_float(u.w & 0xffff0000u);

__global__ __launch_bounds__(256) void k_agg(const unsigned short* __restrict__ hs, const int* __restrict__ rowptr,
                                             const int* __restrict__ esrc, const float* __restrict__ dinv,
                                             const float* __restrict__ bias, float* __restrict__ out,
                                             int n, int relu) {
    int node = blockIdx.x * 16 + (threadIdx.x >> 4);
    int lane = threadIdx.x & 15;
    if (node >= n) return;
    int s = rowptr[node], e = rowptr[node + 1];
    const uint4* h16 = (const uint4*)hs;
    float a0 = 0.f, a1 = 0.f, a2 = 0.f, a3 = 0.f, a4 = 0.f, a5 = 0.f, a6 = 0.f, a7 = 0.f;
    float c0 = 0.f, c1 = 0.f, c2 = 0.f, c3 = 0.f, c4 = 0.f, c5 = 0.f, c6 = 0.f, c7 = 0.f;
    int i = s;
    for (; i + 4 <= e; i += 4) {
        int s0 = esrc[i], s1 = esrc[i + 1], s2 = esrc[i + 2], s3 = esrc[i + 3];
        uint4 u0 = h16[(size_t)s0 * 16 + lane];
        uint4 u1 = h16[(size_t)s1 * 16 + lane];
        uint4 u2 = h16[(size_t)s2 * 16 + lane];
        uint4 u3 = h16[(size_t)s3 * 16 + lane];
        ACC8(a, u0)
        ACC8(c, u1)
        ACC8(a, u2)
        ACC8(c, u3)
    }
    for (; i < e; ++i) {
        uint4 u = h16[(size_t)esrc[i] * 16 + lane];
        ACC8(a, u)
    }
    a0 += c0; a1 += c1; a2 += c2; a3 += c3;
    a4 += c4; a5 += c5; a6 += c6; a7 += c7;
    float di = dinv[node];
    float4 b0 = ((const float4*)bias)[lane * 2];
    float4 b1 = ((const float4*)bias)[lane * 2 + 1];
    float o0 = fmaf(di, a0, b0.x);
    float o1 = fmaf(di, a1, b0.y);
    float o2 = fmaf(di, a2, b0.z);
    float o3 = fmaf(di, a3, b0.w);
    float o4 = fmaf(di, a4, b1.x);
    float o5 = fmaf(di, a5, b1.y);
    float o6 = fmaf(di, a6, b1.z);
    float o7 = fmaf(di, a7, b1.w);
    if (relu) {
        o0 = fmaxf(o0, 0.f); o1 = fmaxf(o1, 0.f); o2 = fmaxf(o2, 0.f); o3 = fmaxf(o3, 0.f);
        o4 = fmaxf(o4, 0.f); o5 = fmaxf(o5, 0.f); o6 = fmaxf(o6, 0.f); o7 = fmaxf(o7, 0.f);
    }
    ((float4*)out)[(size_t)node * 32 + lane * 2]     = make_float4(o0, o1, o2, o3);
    ((float4*)out)[(size_t)node * 32 + lane * 2 + 1] = make_float4(o4, o5, o6, o7);
}

// ---------------- relation offsets: scan + cursor init (folds the old memcpy) ----------------
__global__ void k_roff(const int* __restrict__ rcount, int* __restrict__ roff,
                       int* __restrict__ chunkoff, int* __restrict__ cursor, int nr) {
    if (threadIdx.x == 0 && blockIdx.x == 0) {
        int run = 0, crun = 0;
        for (int r = 0; r < nr; ++r) {
            roff[r] = run; chunkoff[r] = crun; cursor[r] = run;
            run += rcount[r]; crun += (rcount[r] + SC_T - 1) / SC_T;
        }
        roff[nr] = run; chunkoff[nr] = crun;
    }
}

__global__ __launch_bounds__(256) void k_bucket(const int* __restrict__ rel, int* __restrict__ cursor,
                                                int* __restrict__ eidx, int es) {
    __shared__ int lh[16];
    __shared__ int lbase[16];
    int t = threadIdx.x;
    if (t < 16) lh[t] = 0;
    __syncthreads();
    int r[4], lr[4];
#pragma unroll
    for (int i = 0; i < 4; ++i) {
        int e = blockIdx.x * 1024 + i * 256 + t;
        if (e < es) {
            r[i] = rel[e];
            lr[i] = atomicAdd(&lh[r[i]], 1);   // LDS atomic: intra-block rank
        } else r[i] = -1;
    }
    __syncthreads();
    if (t < 16) lbase[t] = lh[t] ? atomicAdd(&cursor[t], lh[t]) : 0;   // reserve range
    __syncthreads();
#pragma unroll
    for (int i = 0; i < 4; ++i)
        if (r[i] >= 0) eidx[lbase[r[i]] + lr[i]] = blockIdx.x * 1024 + i * 256 + t;
}

// ---------------- batched scoring: SC_T triples of ONE relation per block, W[r] staged once ----------------
__global__ __launch_bounds__(256) void k_score_r(const float* __restrict__ z, const float* __restrict__ relW,
                                                 const int* __restrict__ eidx, const int* __restrict__ head,
                                                 const int* __restrict__ tail, const int* __restrict__ roff,
                                                 const int* __restrict__ chunkoff, float* __restrict__ out,
                                                 int R_) {
    __shared__ __align__(16) float Wl[TD * TD];      // 64 KB
    __shared__ __align__(16) float zhL[SC_T * TD];   // 8 KB
    __shared__ __align__(16) float ztL[SC_T * TD];   // 8 KB
    __shared__ int eids[SC_T];
    __shared__ int co[17], ro[17];
    __shared__ float red[4][SC_T];
    const int t = threadIdx.x;
    const int b = blockIdx.x;
    if (t < 17 && t <= R_) { co[t] = chunkoff[t]; ro[t] = roff[t]; }
    __syncthreads();
    int r = 0;
    while (r < R_ && co[r + 1] <= b) ++r;
    if (r >= R_) return;                       // uniform: all threads exit together
    const int base = ro[r] + (b - co[r]) * SC_T;
    const int nt = min(SC_T, ro[r + 1] - base);
    if (t < SC_T) eids[t] = (t < nt) ? eidx[base + t] : -1;
    __syncthreads();
    {   // stage zh/zt: SC_T*32 = 512 float4, 2 per thread
#pragma unroll
        for (int k = 0; k < SC_T * 32 / 256; ++k) {
            int idx = t + k * 256;
            int tt = idx >> 5, c4 = idx & 31;
            float4 vh = make_float4(0.f, 0.f, 0.f, 0.f), vt = vh;
            int e = eids[tt];
            if (e >= 0) {
                vh = ((const float4*)(z + (size_t)head[e] * TD))[c4];
                vt = ((const float4*)(z + (size_t)tail[e] * TD))[c4];
            }
            ((float4*)(zhL + tt * TD))[c4] = vh;
            ((float4*)(ztL + tt * TD))[c4] = vt;
        }
    }
    {   // stage W[r]: 4096 float4
        const float4* W4 = (const float4*)(relW + (size_t)r * TD * TD);
        float4* Wl4 = (float4*)Wl;
#pragma unroll
        for (int i = 0; i < 16; ++i) Wl4[t + i * 256] = W4[t + i * 256];
    }
    __syncthreads();

    const int c  = (t & 31) * 4;    // cols c..c+3
    const int i0 = (t >> 5) * 16;   // 16-row i segment
    float4 acc[SC_T];
#pragma unroll
    for (int u = 0; u < SC_T; ++u) acc[u] = make_float4(0.f, 0.f, 0.f, 0.f);
#pragma unroll 4
    for (int i = i0; i < i0 + 16; ++i) {
        float4 wv = *(const float4*)&Wl[i * TD + c];
#pragma unroll
        for (int u = 0; u < SC_T; ++u) {
            float h = zhL[u * TD + i];
            acc[u].x = fmaf(h, wv.x, acc[u].x);
            acc[u].y = fmaf(h, wv.y, acc[u].y);
            acc[u].z = fmaf(h, wv.z, acc[u].z);
            acc[u].w = fmaf(h, wv.w, acc[u].w);
        }
    }
    float pth[SC_T];
#pragma unroll
    for (int u = 0; u < SC_T; ++u) {
        float4 z4 = *(const float4*)&ztL[u * TD + c];
        pth[u] = acc[u].x * z4.x + acc[u].y * z4.y + acc[u].z * z4.z + acc[u].w * z4.w;
    }
#pragma unroll
    for (int off = 32; off > 0; off >>= 1)
#pragma unroll
        for (int u = 0; u < SC_T; ++u) pth[u] += __shfl_down(pth[u], off);
    if ((t & 63) == 0) {
        int wv = t >> 6;
#pragma unroll
        for (int u = 0; u < SC_T; ++u) red[wv][u] = pth[u];
    }
    __syncthreads();
    if (t < SC_T) {
        int e = eids[t];
        if (e >= 0) out[e] = red[0][t] + red[1][t] + red[2][t] + red[3][t];
    }
}

extern "C" void kernel_launch(void* const* d_in, const int* in_sizes, int n_in,
                              void* d_out, int out_size, void* d_ws, size_t ws_size,
                              hipStream_t stream) {
    const float* x0   = (const float*)d_in[0];
    const float* W1   = (const float*)d_in[1];
    const float* b1   = (const float*)d_in[2];
    const float* W2   = (const float*)d_in[3];
    const float* b2   = (const float*)d_in[4];
    const float* relW = (const float*)d_in[5];
    const int*   ei   = (const int*)d_in[6];
    const int*   rel  = (const int*)d_in[7];
    const int*   head = (const int*)d_in[8];
    const int*   tail = (const int*)d_in[9];
    float* outp = (float*)d_out;

    const int N_  = in_sizes[0] / TD;
    const int E_  = in_sizes[6] / 2;
    const int ES_ = in_sizes[7];
    const int R_  = in_sizes[5] / (TD * TD);
    const int ntiles64 = (N_ + 63) / 64;
    const int ggrid = ntiles64 < 512 ? ntiles64 : 512;   // 2 blocks/CU, persistent W
    const int NB    = (N_ + (1 << BKT_SH) - 1) >> BKT_SH;   // <= 1024 for N <= 131072
    const int chunk  = (E_ + NBLK - 1) / NBLK;
    const int rchunk = (ES_ + NBLK - 1) / NBLK;

    char* p = (char*)d_ws;
    auto alloc = [&](size_t bytes) { char* r = p; p += (bytes + 255) & ~(size_t)255; return r; };
    float*          dinv   = (float*)         alloc((size_t)N_ * 4);
    int*            rowptr = (int*)           alloc(((size_t)N_ + 1) * 4);
    int*            bh     = (int*)           alloc((size_t)NB * NBLK * 4);
    int*            tot    = (int*)           alloc((size_t)NB * 4);
    int*            boff   = (int*)           alloc(((size_t)NB + 1) * 4);
    int*            esrc   = (int*)           alloc((size_t)E_ * 4);
    unsigned short* Wt     = (unsigned short*)alloc((size_t)4 * 16384 * 2);   // W1h,W1l,W2h,W2l
    int*            rcount = (int*)           alloc((size_t)R_ * 4);
    int*            roff   = (int*)           alloc(((size_t)R_ + 1) * 4);
    int*            chkoff = (int*)           alloc(((size_t)R_ + 1) * 4);
    int*            cursor = (int*)           alloc((size_t)R_ * 4);
    int*            eidx   = (int*)           alloc((size_t)ES_ * 4);
    unsigned short* bufA   = (unsigned short*)alloc((size_t)N_ * TD * 2);     // bf16 h-scaled
    float*          bufB   = (float*)         alloc((size_t)N_ * TD * 4);     // f32 conv out
    int*            ebuf   = (int*)bufA;   // alias: dead before first k_gemm writes bufA (E*4 <= N*TD*2)

    hipMemsetAsync(rcount, 0, (size_t)R_ * 4, stream);

    // atomic-free CSR: hist(+rel histo) -> scanA -> scanB -> scatter -> per-bucket build
    kc_hist <<<NBLK, 256, 0, stream>>>(ei, bh, rel, rcount, E_, ES_, NB, chunk, rchunk);
    kc_scanA<<<NB, 64, 0, stream>>>(bh, tot, NB);
    kc_scanB<<<1, 256, 0, stream>>>(tot, boff, NB, rowptr + N_);
    kc_scat <<<NBLK, 256, 0, stream>>>(ei, bh, boff, ebuf, E_, NB, chunk);
    kc_build<<<NB, 256, 0, stream>>>(ebuf, boff, rowptr, dinv, esrc, N_);

    k_wsplit<<<128, 256, 0, stream>>>(W1, W2, Wt);

    // relation bucketing for scoring
    k_roff  <<<1, 64, 0, stream>>>(rcount, roff, chkoff, cursor, R_);
    k_bucket<<<(ES_ + 1023) / 1024, 256, 0, stream>>>(rel, cursor, eidx, ES_);

    // conv1: bufA = bf16(dinv * (x0 @ W1)); bufB = relu(dinv*agg(bufA) + b1)
    k_gemm<<<ggrid, 256, 0, stream>>>(x0, Wt, Wt + 16384, dinv, bufA, N_, ntiles64);
    k_agg <<<(N_ + 15) / 16, 256, 0, stream>>>(bufA, rowptr, esrc, dinv, b1, bufB, N_, 1);
    // conv2: bufA = bf16(dinv * (bufB @ W2)); bufB = dinv*agg(bufA) + b2  (= z)
    k_gemm<<<ggrid, 256, 0, stream>>>(bufB, Wt + 32768, Wt + 49152, dinv, bufA, N_, ntiles64);
    k_agg <<<(N_ + 15) / 16, 256, 0, stream>>>(bufA, rowptr, esrc, dinv, b2, bufB, N_, 0);

    // scoring: blocks = chunks (upper bound ES/SC_T + R); out-of-range blocks exit via chunkoff
    k_score_r<<<(ES_ + SC_T - 1) / SC_T + R_, 256, 0, stream>>>(bufB, relW, eidx, head, tail,
                                                                roff, chkoff, outp, R_);
}

// Round 5
// 356.567 us; speedup vs baseline: 1.2838x; 1.2838x over previous
//
#include <hip/hip_runtime.h>
#include <hip/hip_bf16.h>

#define TD 128    // feature dim, fixed by problem
#define WS 136    // padded W-LDS row stride in bf16 (272 B: 16B-aligned, bank-uniform for b128)
#define SC_T 8    // triples per scoring block (R4 lesson: 16 -> 80KB LDS -> 1 block/CU cliff)
#define BKT_SH 7  // 128 nodes per CSR bucket (NB = ceil(N/128) <= 1024 for N <= 131072)
#define NBLK 256  // partition blocks for hist/scat passes

typedef __attribute__((ext_vector_type(8))) short bf16x8;   // 8 bf16 = 4 VGPR (MFMA A/B frag)
typedef __attribute__((ext_vector_type(4))) float f32x4;    // MFMA C/D frag

static __device__ __forceinline__ unsigned short f2bf(float f) {
    unsigned int u = __float_as_uint(f);
    u += 0x7fffu + ((u >> 16) & 1u);   // round-to-nearest-even
    return (unsigned short)(u >> 16);
}
static __device__ __forceinline__ float bf2f(unsigned short h) {
    return __uint_as_float((unsigned int)h << 16);
}

// ================= atomic-free CSR build =================
// R3: global atomic RMWs hit a ~24 op/ns chip floor with ~32B/op HBM write-through; replaced
// by LDS-histogram multi-split (zero global atomics). R4: k_rcnt folded in here (2nd LDS histo).

// pass 1: per-block bucket histogram (+ relation histogram for scoring bucketing).
__global__ __launch_bounds__(256) void kc_hist(const int* __restrict__ ei, int* __restrict__ bh,
                                               const int* __restrict__ rel, int* __restrict__ rcount,
                                               int E_, int ES_, int NB, int chunk, int rchunk) {
    __shared__ int lh[1024];
    __shared__ int rh[16];
    int t = threadIdx.x, blk = blockIdx.x;
    for (int j = t; j < NB; j += 256) lh[j] = 0;
    if (t < 16) rh[t] = 0;
    __syncthreads();
    int e0 = blk * chunk, e1 = min(E_, e0 + chunk);
    for (int e = e0 + t; e < e1; e += 256)
        atomicAdd(&lh[ei[E_ + e] >> BKT_SH], 1);   // LDS atomic
    int r0 = blk * rchunk, r1 = min(ES_, r0 + rchunk);
    for (int e = r0 + t; e < r1; e += 256)
        atomicAdd(&rh[rel[e]], 1);                 // LDS atomic
    __syncthreads();
    for (int j = t; j < NB; j += 256) bh[(size_t)j * NBLK + blk] = lh[j];
    if (t < 16 && rh[t]) atomicAdd(&rcount[t], rh[t]);   // fire-and-forget, 16/block
}

// pass 2a: per bucket, exclusive scan over the NBLK block counts (in place); tot[b] = bucket size
__global__ __launch_bounds__(64) void kc_scanA(int* __restrict__ bh, int* __restrict__ tot, int NB) {
    int b = blockIdx.x, l = threadIdx.x;
    int* row = bh + (size_t)b * NBLK;
    int run = 0;
#pragma unroll
    for (int g = 0; g < NBLK / 64; ++g) {
        int v = row[g * 64 + l];
        int x = v;
#pragma unroll
        for (int off = 1; off < 64; off <<= 1) {
            int y = __shfl_up(x, off);
            if (l >= off) x += y;
        }
        row[g * 64 + l] = run + x - v;   // exclusive within bucket
        run += __shfl(x, 63);
    }
    if (l == 0) tot[b] = run;
}

// pass 2b: single-block exclusive scan of bucket totals -> boff[0..NB], rowptr[N] = E
__global__ __launch_bounds__(256) void kc_scanB(const int* __restrict__ tot, int* __restrict__ boff,
                                                int NB, int* __restrict__ rowptrN) {
    __shared__ int wsum[4];
    int t = threadIdx.x;
    int base = t * 4;
    int a0 = (base     < NB) ? tot[base]     : 0;
    int a1 = (base + 1 < NB) ? tot[base + 1] : 0;
    int a2 = (base + 2 < NB) ? tot[base + 2] : 0;
    int a3 = (base + 3 < NB) ? tot[base + 3] : 0;
    int s1 = a0 + a1, s2 = s1 + a2, tt = s2 + a3;
    int lane = t & 63, wv = t >> 6;
    int x = tt;
#pragma unroll
    for (int off = 1; off < 64; off <<= 1) {
        int y = __shfl_up(x, off);
        if (lane >= off) x += y;
    }
    if (lane == 63) wsum[wv] = x;
    __syncthreads();
    int woff = 0;
    for (int w = 0; w < wv; ++w) woff += wsum[w];
    int excl = woff + x - tt;
    if (base     < NB) boff[base]     = excl;
    if (base + 1 < NB) boff[base + 1] = excl + a0;
    if (base + 2 < NB) boff[base + 2] = excl + s1;
    if (base + 3 < NB) boff[base + 3] = excl + s2;
    if (t == 255) { boff[NB] = woff + x; *rowptrN = woff + x; }
}

// pass 3: scatter edges into bucket-grouped ebuf, packed (src<<7)|(dst&127). LDS-atomic ranks.
__global__ __launch_bounds__(256) void kc_scat(const int* __restrict__ ei, const int* __restrict__ bh,
                                               const int* __restrict__ boff, int* __restrict__ ebuf,
                                               int E_, int NB, int chunk) {
    __shared__ int lh[1024];
    int t = threadIdx.x, blk = blockIdx.x;
    for (int j = t; j < NB; j += 256) lh[j] = 0;
    __syncthreads();
    int e0 = blk * chunk, e1 = min(E_, e0 + chunk);
    for (int e = e0 + t; e < e1; e += 256) {
        int s = ei[e];
        int d = ei[E_ + e];
        int b = d >> BKT_SH;
        int lr = atomicAdd(&lh[b], 1);   // LDS atomic: rank within (block, bucket)
        int slot = boff[b] + bh[(size_t)b * NBLK + blk] + lr;
        ebuf[slot] = (s << BKT_SH) | (d & ((1 << BKT_SH) - 1));
    }
}

// pass 4: one block per bucket -> exact per-node counting sort. Writes rowptr, dinv, esrc.
__global__ __launch_bounds__(256) void kc_build(const int* __restrict__ ebuf, const int* __restrict__ boff,
                                                int* __restrict__ rowptr, float* __restrict__ dinv,
                                                int* __restrict__ esrc, int n) {
    __shared__ int hist[128], excl[128], cur[128];
    __shared__ int w0;
    int b = blockIdx.x, t = threadIdx.x;
    int node0 = b << BKT_SH;
    int s = boff[b], e = boff[b + 1];
    if (t < 128) { hist[t] = 0; cur[t] = 0; }
    __syncthreads();
    for (int i = s + t; i < e; i += 256)
        atomicAdd(&hist[ebuf[i] & 127], 1);   // LDS atomic
    __syncthreads();
    // scan the 128 counts (waves 0,1 active; uniform syncs)
    int v = (t < 128) ? hist[t] : 0;
    int lane = t & 63, wv = t >> 6;
    int x = v;
#pragma unroll
    for (int off = 1; off < 64; off <<= 1) {
        int y = __shfl_up(x, off);
        if (lane >= off) x += y;
    }
    if (t == 63) w0 = x;
    __syncthreads();
    if (t < 128) {
        int ex = x - v + (wv == 1 ? w0 : 0);
        excl[t] = ex;
        int node = node0 + t;
        if (node < n) {
            rowptr[node] = s + ex;
            dinv[node] = (v > 0) ? 1.0f / sqrtf((float)v) : 0.0f;
        }
    }
    __syncthreads();
    for (int i = s + t; i < e; i += 256) {
        int p = ebuf[i];
        int loc = p & 127;
        int lr = atomicAdd(&cur[loc], 1);   // LDS atomic
        esrc[s + excl[loc] + lr] = p >> BKT_SH;
    }
}

// ---------------- W transpose + hi/lo bf16 split ----------------
__global__ __launch_bounds__(256) void k_wsplit(const float* __restrict__ W1, const float* __restrict__ W2,
                                                unsigned short* __restrict__ Wt) {
    int i = blockIdx.x * 256 + threadIdx.x;   // 0 .. 2*16384-1
    int w = i >> 14;
    int idx = i & 16383;          // = k*128 + n  (coalesced read)
    int k = idx >> 7, n = idx & 127;
    float x = (w ? W2 : W1)[idx];
    unsigned short h = f2bf(x);
    unsigned short l = f2bf(x - bf2f(h));
    size_t base = (size_t)w * 32768;
    Wt[base + n * 128 + k] = h;
    Wt[base + 16384 + n * 128 + k] = l;
}

// ---------------- MFMA GEMM v5 (restored): W hi+lo staged to LDS per block ----------------
// R4 lesson: persistent grid-stride (v6) regressed — with only 2 resident blocks/CU the tile
// loop serializes load->MFMA->store; the dispatcher's stream of fresh blocks IS the pipeline.
// v5: one 64-row tile per block, W staged per block (L2-resident), 1 barrier total.
__global__ __launch_bounds__(256, 2) void k_gemm(const float* __restrict__ X,
                                                 const unsigned short* __restrict__ Wth,
                                                 const unsigned short* __restrict__ Wtl,
                                                 const float* __restrict__ scale,
                                                 unsigned short* __restrict__ out,
                                                 int nrows) {
    __shared__ __align__(16) unsigned short Wl[2][128 * WS];   // 68 KB (hi, lo)
    const int t = threadIdx.x;
    const int w = t >> 6;
    const int lane = t & 63;
    const int l15 = lane & 15;
    const int quad = lane >> 4;
    const int rbase = blockIdx.x * 64 + w * 16;   // wave's 16-row tile
    const int arow = rbase + l15;                 // this lane's A row
    const bool avalid = arow < nrows;

    // A: 8 float4 loads, issue immediately (independent of staging)
    float4 xa[4][2];
#pragma unroll
    for (int kc = 0; kc < 4; ++kc) {
        const float* src = X + (size_t)arow * TD + kc * 32 + quad * 8;
        xa[kc][0] = avalid ? *(const float4*)src       : make_float4(0.f, 0.f, 0.f, 0.f);
        xa[kc][1] = avalid ? *(const float4*)(src + 4) : make_float4(0.f, 0.f, 0.f, 0.f);
    }

    // stage W hi+lo -> padded LDS: 2048 uint4 per plane, 8 per thread
    {
        const uint4* gh = (const uint4*)Wth;
        const uint4* gl = (const uint4*)Wtl;
#pragma unroll
        for (int it = 0; it < 8; ++it) {
            int idx = t + it * 256;            // 0..2047
            int n = idx >> 4, kg = idx & 15;   // row n, k-group kg (8 bf16 each)
            uint4 vh = gh[idx];
            uint4 vl = gl[idx];
            *(uint4*)&Wl[0][n * WS + kg * 8] = vh;
            *(uint4*)&Wl[1][n * WS + kg * 8] = vl;
        }
    }

    // convert A to bf16 hi/lo fragments while staging is in flight
    bf16x8 ah[4], al[4];
#pragma unroll
    for (int kc = 0; kc < 4; ++kc) {
#pragma unroll
        for (int j = 0; j < 8; ++j) {
            float v = (j < 4) ? ((const float*)&xa[kc][0])[j] : ((const float*)&xa[kc][1])[j - 4];
            unsigned short h = f2bf(v);
            ah[kc][j] = (short)h;
            al[kc][j] = (short)f2bf(v - bf2f(h));
        }
    }
    __syncthreads();

    f32x4 acc[8];
#pragma unroll
    for (int b = 0; b < 8; ++b) acc[b] = (f32x4){0.f, 0.f, 0.f, 0.f};

#pragma unroll
    for (int kc = 0; kc < 4; ++kc) {
        const int koff = kc * 32 + quad * 8;
#pragma unroll
        for (int b = 0; b < 8; ++b) {
            const int boff = (b * 16 + l15) * WS + koff;
            bf16x8 bh = *(const bf16x8*)&Wl[0][boff];
            bf16x8 bl = *(const bf16x8*)&Wl[1][boff];
            acc[b] = __builtin_amdgcn_mfma_f32_16x16x32_bf16(ah[kc], bh, acc[b], 0, 0, 0);
            acc[b] = __builtin_amdgcn_mfma_f32_16x16x32_bf16(al[kc], bh, acc[b], 0, 0, 0);
            acc[b] = __builtin_amdgcn_mfma_f32_16x16x32_bf16(ah[kc], bl, acc[b], 0, 0, 0);
        }
    }

    // epilogue: C/D layout col=lane&15, row=quad*4+reg -> scale + direct bf16 global stores
    {
        int grow = rbase + quad * 4;              // multiple of 4; nrows % 4 == 0
        if (grow < nrows) {
            float4 s4 = *(const float4*)&scale[grow];
#pragma unroll
            for (int b = 0; b < 8; ++b) {
                int col = b * 16 + l15;
                out[(size_t)(grow + 0) * TD + col] = f2bf(acc[b][0] * s4.x);
                out[(size_t)(grow + 1) * TD + col] = f2bf(acc[b][1] * s4.y);
                out[(size_t)(grow + 2) * TD + col] = f2bf(acc[b][2] * s4.z);
                out[(size_t)(grow + 3) * TD + col] = f2bf(acc[b][3] * s4.w);
            }
        }
    }
}

// ---------------- CSR aggregation: bf16 gather, f32 accumulate, 4-edge unrolled ----------------
// R3 counters: 230MB L2-miss traffic in 63us = 3.65 TB/s = the random-256B-gather pattern
// ceiling (compulsory per-XCD misses: 25.6MB bufA x 8 XCDs; random 64B/channel DRAM access).
// VALUBusy 27%. At bf16 this kernel is at its roofline; left byte-identical.
#define ACC8(p, u) \
    p##0 += __uint_as_float(u.x << 16); p##1 += __uint_as_float(u.x & 0xffff0000u); \
    p##2 += __uint_as_float(u.y << 16); p##3 += __uint_as_float(u.y & 0xffff0000u); \
    p##4 += __uint_as_float(u.z << 16); p##5 += __uint_as_float(u.z & 0xffff0000u); \
    p##6 += __uint_as_float(u.w << 16); p##7 += __uint_as_float(u.w & 0xffff0000u);

__global__ __launch_bounds__(256) void k_agg(const unsigned short* __restrict__ hs, const int* __restrict__ rowptr,
                                             const int* __restrict__ esrc, const float* __restrict__ dinv,
                                             const float* __restrict__ bias, float* __restrict__ out,
                                             int n, int relu) {
    int node = blockIdx.x * 16 + (threadIdx.x >> 4);
    int lane = threadIdx.x & 15;
    if (node >= n) return;
    int s = rowptr[node], e = rowptr[node + 1];
    const uint4* h16 = (const uint4*)hs;
    float a0 = 0.f, a1 = 0.f, a2 = 0.f, a3 = 0.f, a4 = 0.f, a5 = 0.f, a6 = 0.f, a7 = 0.f;
    float c0 = 0.f, c1 = 0.f, c2 = 0.f, c3 = 0.f, c4 = 0.f, c5 = 0.f, c6 = 0.f, c7 = 0.f;
    int i = s;
    for (; i + 4 <= e; i += 4) {
        int s0 = esrc[i], s1 = esrc[i + 1], s2 = esrc[i + 2], s3 = esrc[i + 3];
        uint4 u0 = h16[(size_t)s0 * 16 + lane];
        uint4 u1 = h16[(size_t)s1 * 16 + lane];
        uint4 u2 = h16[(size_t)s2 * 16 + lane];
        uint4 u3 = h16[(size_t)s3 * 16 + lane];
        ACC8(a, u0)
        ACC8(c, u1)
        ACC8(a, u2)
        ACC8(c, u3)
    }
    for (; i < e; ++i) {
        uint4 u = h16[(size_t)esrc[i] * 16 + lane];
        ACC8(a, u)
    }
    a0 += c0; a1 += c1; a2 += c2; a3 += c3;
    a4 += c4; a5 += c5; a6 += c6; a7 += c7;
    float di = dinv[node];
    float4 b0 = ((const float4*)bias)[lane * 2];
    float4 b1 = ((const float4*)bias)[lane * 2 + 1];
    float o0 = fmaf(di, a0, b0.x);
    float o1 = fmaf(di, a1, b0.y);
    float o2 = fmaf(di, a2, b0.z);
    float o3 = fmaf(di, a3, b0.w);
    float o4 = fmaf(di, a4, b1.x);
    float o5 = fmaf(di, a5, b1.y);
    float o6 = fmaf(di, a6, b1.z);
    float o7 = fmaf(di, a7, b1.w);
    if (relu) {
        o0 = fmaxf(o0, 0.f); o1 = fmaxf(o1, 0.f); o2 = fmaxf(o2, 0.f); o3 = fmaxf(o3, 0.f);
        o4 = fmaxf(o4, 0.f); o5 = fmaxf(o5, 0.f); o6 = fmaxf(o6, 0.f); o7 = fmaxf(o7, 0.f);
    }
    ((float4*)out)[(size_t)node * 32 + lane * 2]     = make_float4(o0, o1, o2, o3);
    ((float4*)out)[(size_t)node * 32 + lane * 2 + 1] = make_float4(o4, o5, o6, o7);
}

// ---------------- relation offsets: scan + cursor init ----------------
__global__ void k_roff(const int* __restrict__ rcount, int* __restrict__ roff,
                       int* __restrict__ chunkoff, int* __restrict__ cursor, int nr) {
    if (threadIdx.x == 0 && blockIdx.x == 0) {
        int run = 0, crun = 0;
        for (int r = 0; r < nr; ++r) {
            roff[r] = run; chunkoff[r] = crun; cursor[r] = run;
            run += rcount[r]; crun += (rcount[r] + SC_T - 1) / SC_T;
        }
        roff[nr] = run; chunkoff[nr] = crun;
    }
}

__global__ __launch_bounds__(256) void k_bucket(const int* __restrict__ rel, int* __restrict__ cursor,
                                                int* __restrict__ eidx, int es) {
    __shared__ int lh[16];
    __shared__ int lbase[16];
    int t = threadIdx.x;
    if (t < 16) lh[t] = 0;
    __syncthreads();
    int r[4], lr[4];
#pragma unroll
    for (int i = 0; i < 4; ++i) {
        int e = blockIdx.x * 1024 + i * 256 + t;
        if (e < es) {
            r[i] = rel[e];
            lr[i] = atomicAdd(&lh[r[i]], 1);   // LDS atomic: intra-block rank
        } else r[i] = -1;
    }
    __syncthreads();
    if (t < 16) lbase[t] = lh[t] ? atomicAdd(&cursor[t], lh[t]) : 0;   // reserve range
    __syncthreads();
#pragma unroll
    for (int i = 0; i < 4; ++i)
        if (r[i] >= 0) eidx[lbase[r[i]] + lr[i]] = blockIdx.x * 1024 + i * 256 + t;
}

// ---------------- batched scoring v3: contiguous chunk range per block, W[r] cached ----------------
// R5: SC_T=8 (72.5KB LDS -> 2 blocks/CU, the R4 occupancy cliff undone). Each block owns a
// CONTIGUOUS range of chunks; chunks of one relation are consecutive, so W[r] is re-staged
// only on relation change (~3% of steps): W->LDS traffic 240MB -> ~35MB at unchanged
// occupancy and per-chunk structure.
__global__ __launch_bounds__(256) void k_score_r(const float* __restrict__ z, const float* __restrict__ relW,
                                                 const int* __restrict__ eidx, const int* __restrict__ head,
                                                 const int* __restrict__ tail, const int* __restrict__ roff,
                                                 const int* __restrict__ chunkoff, float* __restrict__ out,
                                                 int R_, int cpb) {
    __shared__ __align__(16) float Wl[TD * TD];      // 64 KB
    __shared__ __align__(16) float zhL[SC_T * TD];   // 4 KB
    __shared__ __align__(16) float ztL[SC_T * TD];   // 4 KB
    __shared__ int eids[SC_T];
    __shared__ int co[17], ro[17];
    __shared__ float red[4][SC_T];
    const int t = threadIdx.x;
    if (t < 17 && t <= R_) { co[t] = chunkoff[t]; ro[t] = roff[t]; }
    __syncthreads();
    const int nch = co[R_];                    // total real chunks
    int b = blockIdx.x * cpb;
    const int bend = min(nch, b + cpb);
    int r = 0, rprev = -1;
    for (; b < bend; ++b) {
        while (co[r + 1] <= b) ++r;            // monotone in b; uniform across block
        const int base = ro[r] + (b - co[r]) * SC_T;
        const int nt = min(SC_T, ro[r + 1] - base);
        if (t < SC_T) eids[t] = (t < nt) ? eidx[base + t] : -1;
        const bool newW = (r != rprev);
        rprev = r;
        __syncthreads();                       // eids visible; zhL free (post-compute barrier)
        {   // stage zh/zt: 256 float4, 1 per thread
            int tt = t >> 5, c4 = t & 31;
            float4 vh = make_float4(0.f, 0.f, 0.f, 0.f), vt = vh;
            int e = eids[tt];
            if (e >= 0) {
                vh = ((const float4*)(z + (size_t)head[e] * TD))[c4];
                vt = ((const float4*)(z + (size_t)tail[e] * TD))[c4];
            }
            ((float4*)(zhL + tt * TD))[c4] = vh;
            ((float4*)(ztL + tt * TD))[c4] = vt;
        }
        if (newW) {   // stage W[r]: 4096 float4 (only on relation change)
            const float4* W4 = (const float4*)(relW + (size_t)r * TD * TD);
            float4* Wl4 = (float4*)Wl;
#pragma unroll
            for (int i = 0; i < 16; ++i) Wl4[t + i * 256] = W4[t + i * 256];
        }
        __syncthreads();

        const int c  = (t & 31) * 4;    // cols c..c+3
        const int i0 = (t >> 5) * 16;   // 16-row i segment
        float4 acc[SC_T];
#pragma unroll
        for (int u = 0; u < SC_T; ++u) acc[u] = make_float4(0.f, 0.f, 0.f, 0.f);
#pragma unroll 4
        for (int i = i0; i < i0 + 16; ++i) {
            float4 wv = *(const float4*)&Wl[i * TD + c];
#pragma unroll
            for (int u = 0; u < SC_T; ++u) {
                float h = zhL[u * TD + i];
                acc[u].x = fmaf(h, wv.x, acc[u].x);
                acc[u].y = fmaf(h, wv.y, acc[u].y);
                acc[u].z = fmaf(h, wv.z, acc[u].z);
                acc[u].w = fmaf(h, wv.w, acc[u].w);
            }
        }
        float pth[SC_T];
#pragma unroll
        for (int u = 0; u < SC_T; ++u) {
            float4 z4 = *(const float4*)&ztL[u * TD + c];
            pth[u] = acc[u].x * z4.x + acc[u].y * z4.y + acc[u].z * z4.z + acc[u].w * z4.w;
        }
#pragma unroll
        for (int off = 32; off > 0; off >>= 1)
#pragma unroll
            for (int u = 0; u < SC_T; ++u) pth[u] += __shfl_down(pth[u], off);
        if ((t & 63) == 0) {
            int wv = t >> 6;
#pragma unroll
            for (int u = 0; u < SC_T; ++u) red[wv][u] = pth[u];
        }
        __syncthreads();
        if (t < SC_T) {
            int e = eids[t];
            if (e >= 0) out[e] = red[0][t] + red[1][t] + red[2][t] + red[3][t];
        }
    }
}

extern "C" void kernel_launch(void* const* d_in, const int* in_sizes, int n_in,
                              void* d_out, int out_size, void* d_ws, size_t ws_size,
                              hipStream_t stream) {
    const float* x0   = (const float*)d_in[0];
    const float* W1   = (const float*)d_in[1];
    const float* b1   = (const float*)d_in[2];
    const float* W2   = (const float*)d_in[3];
    const float* b2   = (const float*)d_in[4];
    const float* relW = (const float*)d_in[5];
    const int*   ei   = (const int*)d_in[6];
    const int*   rel  = (const int*)d_in[7];
    const int*   head = (const int*)d_in[8];
    const int*   tail = (const int*)d_in[9];
    float* outp = (float*)d_out;

    const int N_  = in_sizes[0] / TD;
    const int E_  = in_sizes[6] / 2;
    const int ES_ = in_sizes[7];
    const int R_  = in_sizes[5] / (TD * TD);
    const int ntiles64 = (N_ + 63) / 64;
    const int NB    = (N_ + (1 << BKT_SH) - 1) >> BKT_SH;   // <= 1024 for N <= 131072
    const int chunk  = (E_ + NBLK - 1) / NBLK;
    const int rchunk = (ES_ + NBLK - 1) / NBLK;
    const int maxch  = (ES_ + SC_T - 1) / SC_T + R_;        // upper bound on chunk count
    const int sgrid  = maxch < 512 ? maxch : 512;           // 2 blocks/CU
    const int cpb    = (maxch + sgrid - 1) / sgrid;         // chunks per block (contiguous)

    char* p = (char*)d_ws;
    auto alloc = [&](size_t bytes) { char* r = p; p += (bytes + 255) & ~(size_t)255; return r; };
    float*          dinv   = (float*)         alloc((size_t)N_ * 4);
    int*            rowptr = (int*)           alloc(((size_t)N_ + 1) * 4);
    int*            bh     = (int*)           alloc((size_t)NB * NBLK * 4);
    int*            tot    = (int*)           alloc((size_t)NB * 4);
    int*            boff   = (int*)           alloc(((size_t)NB + 1) * 4);
    int*            esrc   = (int*)           alloc((size_t)E_ * 4);
    unsigned short* Wt     = (unsigned short*)alloc((size_t)4 * 16384 * 2);   // W1h,W1l,W2h,W2l
    int*            rcount = (int*)           alloc((size_t)R_ * 4);
    int*            roff   = (int*)           alloc(((size_t)R_ + 1) * 4);
    int*            chkoff = (int*)           alloc(((size_t)R_ + 1) * 4);
    int*            cursor = (int*)           alloc((size_t)R_ * 4);
    int*            eidx   = (int*)           alloc((size_t)ES_ * 4);
    unsigned short* bufA   = (unsigned short*)alloc((size_t)N_ * TD * 2);     // bf16 h-scaled
    float*          bufB   = (float*)         alloc((size_t)N_ * TD * 4);     // f32 conv out
    int*            ebuf   = (int*)bufA;   // alias: dead before first k_gemm writes bufA (E*4 <= N*TD*2)

    hipMemsetAsync(rcount, 0, (size_t)R_ * 4, stream);

    // atomic-free CSR: hist(+rel histo) -> scanA -> scanB -> scatter -> per-bucket build
    kc_hist <<<NBLK, 256, 0, stream>>>(ei, bh, rel, rcount, E_, ES_, NB, chunk, rchunk);
    kc_scanA<<<NB, 64, 0, stream>>>(bh, tot, NB);
    kc_scanB<<<1, 256, 0, stream>>>(tot, boff, NB, rowptr + N_);
    kc_scat <<<NBLK, 256, 0, stream>>>(ei, bh, boff, ebuf, E_, NB, chunk);
    kc_build<<<NB, 256, 0, stream>>>(ebuf, boff, rowptr, dinv, esrc, N_);

    k_wsplit<<<128, 256, 0, stream>>>(W1, W2, Wt);

    // relation bucketing for scoring
    k_roff  <<<1, 64, 0, stream>>>(rcount, roff, chkoff, cursor, R_);
    k_bucket<<<(ES_ + 1023) / 1024, 256, 0, stream>>>(rel, cursor, eidx, ES_);

    // conv1: bufA = bf16(dinv * (x0 @ W1)); bufB = relu(dinv*agg(bufA) + b1)
    k_gemm<<<ntiles64, 256, 0, stream>>>(x0, Wt, Wt + 16384, dinv, bufA, N_);
    k_agg <<<(N_ + 15) / 16, 256, 0, stream>>>(bufA, rowptr, esrc, dinv, b1, bufB, N_, 1);
    // conv2: bufA = bf16(dinv * (bufB @ W2)); bufB = dinv*agg(bufA) + b2  (= z)
    k_gemm<<<ntiles64, 256, 0, stream>>>(bufB, Wt + 32768, Wt + 49152, dinv, bufA, N_);
    k_agg <<<(N_ + 15) / 16, 256, 0, stream>>>(bufA, rowptr, esrc, dinv, b2, bufB, N_, 0);

    // scoring: contiguous chunk ranges, W cached across same-relation chunks
    k_score_r<<<sgrid, 256, 0, stream>>>(bufB, relW, eidx, head, tail,
                                         roff, chkoff, outp, R_, cpb);
}

// Round 6
// 326.071 us; speedup vs baseline: 1.4039x; 1.0935x over previous
//
#include <hip/hip_runtime.h>
#include <hip/hip_bf16.h>

#define TD 128    // feature dim, fixed by problem
#define WS 136    // padded W-LDS row stride in bf16 (272 B: 16B-aligned, bank-uniform for b128)
#define SC_T 8    // triples per scoring block (R4 lesson: 16 -> 80KB LDS -> 1 block/CU cliff)
#define BKT_SH 7  // 128 nodes per CSR bucket (NB = ceil(N/128) <= 1024 for N <= 131072)
#define NBLK 256  // partition blocks for hist/scat passes

typedef __attribute__((ext_vector_type(8))) short bf16x8;   // 8 bf16 = 4 VGPR (MFMA A/B frag)
typedef __attribute__((ext_vector_type(4))) float f32x4;    // MFMA C/D frag

static __device__ __forceinline__ unsigned short f2bf(float f) {
    unsigned int u = __float_as_uint(f);
    u += 0x7fffu + ((u >> 16) & 1u);   // round-to-nearest-even
    return (unsigned short)(u >> 16);
}
static __device__ __forceinline__ float bf2f(unsigned short h) {
    return __uint_as_float((unsigned int)h << 16);
}

// ================= atomic-free CSR build =================
// R3: global atomic RMWs hit a ~24 op/ns chip floor with ~32B/op HBM write-through; replaced
// by LDS-histogram multi-split (zero global atomics). R4: k_rcnt folded in here (2nd LDS histo).

// pass 1: per-block bucket histogram (+ relation histogram for scoring bucketing).
__global__ __launch_bounds__(256) void kc_hist(const int* __restrict__ ei, int* __restrict__ bh,
                                               const int* __restrict__ rel, int* __restrict__ rcount,
                                               int E_, int ES_, int NB, int chunk, int rchunk) {
    __shared__ int lh[1024];
    __shared__ int rh[16];
    int t = threadIdx.x, blk = blockIdx.x;
    for (int j = t; j < NB; j += 256) lh[j] = 0;
    if (t < 16) rh[t] = 0;
    __syncthreads();
    int e0 = blk * chunk, e1 = min(E_, e0 + chunk);
    for (int e = e0 + t; e < e1; e += 256)
        atomicAdd(&lh[ei[E_ + e] >> BKT_SH], 1);   // LDS atomic
    int r0 = blk * rchunk, r1 = min(ES_, r0 + rchunk);
    for (int e = r0 + t; e < r1; e += 256)
        atomicAdd(&rh[rel[e]], 1);                 // LDS atomic
    __syncthreads();
    for (int j = t; j < NB; j += 256) bh[(size_t)j * NBLK + blk] = lh[j];
    if (t < 16 && rh[t]) atomicAdd(&rcount[t], rh[t]);   // fire-and-forget, 16/block
}

// pass 2a: per bucket, exclusive scan over the NBLK block counts (in place); tot[b] = bucket size
__global__ __launch_bounds__(64) void kc_scanA(int* __restrict__ bh, int* __restrict__ tot, int NB) {
    int b = blockIdx.x, l = threadIdx.x;
    int* row = bh + (size_t)b * NBLK;
    int run = 0;
#pragma unroll
    for (int g = 0; g < NBLK / 64; ++g) {
        int v = row[g * 64 + l];
        int x = v;
#pragma unroll
        for (int off = 1; off < 64; off <<= 1) {
            int y = __shfl_up(x, off);
            if (l >= off) x += y;
        }
        row[g * 64 + l] = run + x - v;   // exclusive within bucket
        run += __shfl(x, 63);
    }
    if (l == 0) tot[b] = run;
}

// pass 2b: single-block exclusive scan of bucket totals -> boff[0..NB], rowptr[N] = E
__global__ __launch_bounds__(256) void kc_scanB(const int* __restrict__ tot, int* __restrict__ boff,
                                                int NB, int* __restrict__ rowptrN) {
    __shared__ int wsum[4];
    int t = threadIdx.x;
    int base = t * 4;
    int a0 = (base     < NB) ? tot[base]     : 0;
    int a1 = (base + 1 < NB) ? tot[base + 1] : 0;
    int a2 = (base + 2 < NB) ? tot[base + 2] : 0;
    int a3 = (base + 3 < NB) ? tot[base + 3] : 0;
    int s1 = a0 + a1, s2 = s1 + a2, tt = s2 + a3;
    int lane = t & 63, wv = t >> 6;
    int x = tt;
#pragma unroll
    for (int off = 1; off < 64; off <<= 1) {
        int y = __shfl_up(x, off);
        if (lane >= off) x += y;
    }
    if (lane == 63) wsum[wv] = x;
    __syncthreads();
    int woff = 0;
    for (int w = 0; w < wv; ++w) woff += wsum[w];
    int excl = woff + x - tt;
    if (base     < NB) boff[base]     = excl;
    if (base + 1 < NB) boff[base + 1] = excl + a0;
    if (base + 2 < NB) boff[base + 2] = excl + s1;
    if (base + 3 < NB) boff[base + 3] = excl + s2;
    if (t == 255) { boff[NB] = woff + x; *rowptrN = woff + x; }
}

// pass 3: scatter edges into bucket-grouped ebuf, packed (src<<7)|(dst&127). LDS-atomic ranks.
__global__ __launch_bounds__(256) void kc_scat(const int* __restrict__ ei, const int* __restrict__ bh,
                                               const int* __restrict__ boff, int* __restrict__ ebuf,
                                               int E_, int NB, int chunk) {
    __shared__ int lh[1024];
    int t = threadIdx.x, blk = blockIdx.x;
    for (int j = t; j < NB; j += 256) lh[j] = 0;
    __syncthreads();
    int e0 = blk * chunk, e1 = min(E_, e0 + chunk);
    for (int e = e0 + t; e < e1; e += 256) {
        int s = ei[e];
        int d = ei[E_ + e];
        int b = d >> BKT_SH;
        int lr = atomicAdd(&lh[b], 1);   // LDS atomic: rank within (block, bucket)
        int slot = boff[b] + bh[(size_t)b * NBLK + blk] + lr;
        ebuf[slot] = (s << BKT_SH) | (d & ((1 << BKT_SH) - 1));
    }
}

// pass 4: one block per bucket -> exact per-node counting sort. Writes rowptr, dinv, esrc.
__global__ __launch_bounds__(256) void kc_build(const int* __restrict__ ebuf, const int* __restrict__ boff,
                                                int* __restrict__ rowptr, float* __restrict__ dinv,
                                                int* __restrict__ esrc, int n) {
    __shared__ int hist[128], excl[128], cur[128];
    __shared__ int w0;
    int b = blockIdx.x, t = threadIdx.x;
    int node0 = b << BKT_SH;
    int s = boff[b], e = boff[b + 1];
    if (t < 128) { hist[t] = 0; cur[t] = 0; }
    __syncthreads();
    for (int i = s + t; i < e; i += 256)
        atomicAdd(&hist[ebuf[i] & 127], 1);   // LDS atomic
    __syncthreads();
    // scan the 128 counts (waves 0,1 active; uniform syncs)
    int v = (t < 128) ? hist[t] : 0;
    int lane = t & 63, wv = t >> 6;
    int x = v;
#pragma unroll
    for (int off = 1; off < 64; off <<= 1) {
        int y = __shfl_up(x, off);
        if (lane >= off) x += y;
    }
    if (t == 63) w0 = x;
    __syncthreads();
    if (t < 128) {
        int ex = x - v + (wv == 1 ? w0 : 0);
        excl[t] = ex;
        int node = node0 + t;
        if (node < n) {
            rowptr[node] = s + ex;
            dinv[node] = (v > 0) ? 1.0f / sqrtf((float)v) : 0.0f;
        }
    }
    __syncthreads();
    for (int i = s + t; i < e; i += 256) {
        int p = ebuf[i];
        int loc = p & 127;
        int lr = atomicAdd(&cur[loc], 1);   // LDS atomic
        esrc[s + excl[loc] + lr] = p >> BKT_SH;
    }
}

// ---------------- W transpose + hi/lo bf16 split ----------------
__global__ __launch_bounds__(256) void k_wsplit(const float* __restrict__ W1, const float* __restrict__ W2,
                                                unsigned short* __restrict__ Wt) {
    int i = blockIdx.x * 256 + threadIdx.x;   // 0 .. 2*16384-1
    int w = i >> 14;
    int idx = i & 16383;          // = k*128 + n  (coalesced read)
    int k = idx >> 7, n = idx & 127;
    float x = (w ? W2 : W1)[idx];
    unsigned short h = f2bf(x);
    unsigned short l = f2bf(x - bf2f(h));
    size_t base = (size_t)w * 32768;
    Wt[base + n * 128 + k] = h;
    Wt[base + 16384 + n * 128 + k] = l;
}

// ---------------- MFMA GEMM v7: v5 + int8 per-row-quantized output ----------------
// R6: k_agg is at the bf16 random-gather roofline (R5 counters: 3.7 TB/s on compulsory
// per-XCD misses). Halve the row bytes: epilogue computes per-row max (4x shfl_xor over the
// 16-lane group), quantizes to int8 (q = rint(127*m/rowmax)), transposes via the now-free
// W-LDS (byte writes -> barrier -> linear coalesced dword copy), writes sc[row]=rowmax/127.
// Error budget: int8-per-rowmax ~15x bf16 noise/layer => predicted absmax ~1-3e-6 (was 2.4e-7).
__global__ __launch_bounds__(256, 2) void k_gemm(const float* __restrict__ X,
                                                 const unsigned short* __restrict__ Wth,
                                                 const unsigned short* __restrict__ Wtl,
                                                 const float* __restrict__ scale,
                                                 unsigned char* __restrict__ out8,
                                                 float* __restrict__ scOut,
                                                 int nrows) {
    __shared__ __align__(16) unsigned short Wl[2][128 * WS];   // 68 KB (hi, lo); reused by epilogue
    const int t = threadIdx.x;
    const int w = t >> 6;
    const int lane = t & 63;
    const int l15 = lane & 15;
    const int quad = lane >> 4;
    const int rbase = blockIdx.x * 64 + w * 16;   // wave's 16-row tile
    const int arow = rbase + l15;                 // this lane's A row
    const bool avalid = arow < nrows;

    // A: 8 float4 loads, issue immediately (independent of staging)
    float4 xa[4][2];
#pragma unroll
    for (int kc = 0; kc < 4; ++kc) {
        const float* src = X + (size_t)arow * TD + kc * 32 + quad * 8;
        xa[kc][0] = avalid ? *(const float4*)src       : make_float4(0.f, 0.f, 0.f, 0.f);
        xa[kc][1] = avalid ? *(const float4*)(src + 4) : make_float4(0.f, 0.f, 0.f, 0.f);
    }

    // stage W hi+lo -> padded LDS: 2048 uint4 per plane, 8 per thread
    {
        const uint4* gh = (const uint4*)Wth;
        const uint4* gl = (const uint4*)Wtl;
#pragma unroll
        for (int it = 0; it < 8; ++it) {
            int idx = t + it * 256;            // 0..2047
            int n = idx >> 4, kg = idx & 15;   // row n, k-group kg (8 bf16 each)
            uint4 vh = gh[idx];
            uint4 vl = gl[idx];
            *(uint4*)&Wl[0][n * WS + kg * 8] = vh;
            *(uint4*)&Wl[1][n * WS + kg * 8] = vl;
        }
    }

    // convert A to bf16 hi/lo fragments while staging is in flight
    bf16x8 ah[4], al[4];
#pragma unroll
    for (int kc = 0; kc < 4; ++kc) {
#pragma unroll
        for (int j = 0; j < 8; ++j) {
            float v = (j < 4) ? ((const float*)&xa[kc][0])[j] : ((const float*)&xa[kc][1])[j - 4];
            unsigned short h = f2bf(v);
            ah[kc][j] = (short)h;
            al[kc][j] = (short)f2bf(v - bf2f(h));
        }
    }
    __syncthreads();

    f32x4 acc[8];
#pragma unroll
    for (int b = 0; b < 8; ++b) acc[b] = (f32x4){0.f, 0.f, 0.f, 0.f};

#pragma unroll
    for (int kc = 0; kc < 4; ++kc) {
        const int koff = kc * 32 + quad * 8;
#pragma unroll
        for (int b = 0; b < 8; ++b) {
            const int boff = (b * 16 + l15) * WS + koff;
            bf16x8 bh = *(const bf16x8*)&Wl[0][boff];
            bf16x8 bl = *(const bf16x8*)&Wl[1][boff];
            acc[b] = __builtin_amdgcn_mfma_f32_16x16x32_bf16(ah[kc], bh, acc[b], 0, 0, 0);
            acc[b] = __builtin_amdgcn_mfma_f32_16x16x32_bf16(al[kc], bh, acc[b], 0, 0, 0);
            acc[b] = __builtin_amdgcn_mfma_f32_16x16x32_bf16(ah[kc], bl, acc[b], 0, 0, 0);
        }
    }

    __syncthreads();   // all waves done reading Wl -> safe to reuse as transpose buffer

    // epilogue: m = acc*dinv; rowmax over 16 lanes; int8 quantize; LDS byte transpose
    {
        unsigned char* lds8 = (unsigned char*)&Wl[0][0];
        const int grow = rbase + quad * 4;        // multiple of 4; nrows % 4 == 0
        float4 s4 = make_float4(0.f, 0.f, 0.f, 0.f);
        if (grow < nrows) s4 = *(const float4*)&scale[grow];
        float rm[4];
#pragma unroll
        for (int j = 0; j < 4; ++j) {
            float sj = ((const float*)&s4)[j];
            float mx = 0.f;
#pragma unroll
            for (int b = 0; b < 8; ++b) {
                acc[b][j] *= sj;
                mx = fmaxf(mx, fabsf(acc[b][j]));
            }
            rm[j] = mx;
        }
#pragma unroll
        for (int m_ = 1; m_ < 16; m_ <<= 1)
#pragma unroll
            for (int j = 0; j < 4; ++j) rm[j] = fmaxf(rm[j], __shfl_xor(rm[j], m_));
        float inv[4];
#pragma unroll
        for (int j = 0; j < 4; ++j) inv[j] = rm[j] > 0.f ? 127.f / rm[j] : 0.f;
#pragma unroll
        for (int j = 0; j < 4; ++j) {
            int lrow = w * 16 + quad * 4 + j;
#pragma unroll
            for (int b = 0; b < 8; ++b) {
                int q = (int)rintf(acc[b][j] * inv[j]);
                lds8[lrow * 128 + b * 16 + l15] = (unsigned char)(signed char)q;
            }
        }
        if (l15 == 0 && grow < nrows)
            *(float4*)&scOut[grow] = make_float4(rm[0] * (1.f / 127.f), rm[1] * (1.f / 127.f),
                                                 rm[2] * (1.f / 127.f), rm[3] * (1.f / 127.f));
    }
    __syncthreads();
    {   // linear coalesced copy: 2048 dwords (64 rows x 128 B)
        const unsigned int* lds32 = (const unsigned int*)&Wl[0][0];
        unsigned int* g32 = (unsigned int*)out8;
#pragma unroll
        for (int k = 0; k < 8; ++k) {
            int idx = t + k * 256;
            int row = blockIdx.x * 64 + (idx >> 5);
            if (row < nrows) g32[(size_t)blockIdx.x * 2048 + idx] = lds32[idx];
        }
    }
}

// ---------------- CSR aggregation v2: int8 gather + per-row scale, f32 accumulate ----------------
// Row bytes 256 -> 128 (+4B scale from a 400KB L2-resident array). Dequant = bfe+cvt+fma
// per element (VALUBusy 27% -> ~40%, still under the memory floor). Same 4-edge / 2-bank MLP.
#define ACCI8(p, u, s) \
    p##0 = fmaf(s, (float)(signed char)(u.x      ), p##0); \
    p##1 = fmaf(s, (float)(signed char)(u.x >>  8), p##1); \
    p##2 = fmaf(s, (float)(signed char)(u.x >> 16), p##2); \
    p##3 = fmaf(s, (float)(signed char)(u.x >> 24), p##3); \
    p##4 = fmaf(s, (float)(signed char)(u.y      ), p##4); \
    p##5 = fmaf(s, (float)(signed char)(u.y >>  8), p##5); \
    p##6 = fmaf(s, (float)(signed char)(u.y >> 16), p##6); \
    p##7 = fmaf(s, (float)(signed char)(u.y >> 24), p##7);

__global__ __launch_bounds__(256) void k_agg(const unsigned char* __restrict__ hs8, const float* __restrict__ sc,
                                             const int* __restrict__ rowptr, const int* __restrict__ esrc,
                                             const float* __restrict__ dinv, const float* __restrict__ bias,
                                             float* __restrict__ out, int n, int relu) {
    int node = blockIdx.x * 16 + (threadIdx.x >> 4);
    int lane = threadIdx.x & 15;
    if (node >= n) return;
    int s = rowptr[node], e = rowptr[node + 1];
    const uint2* h8 = (const uint2*)hs8;   // 16 lanes x 8B = one 128B int8 row
    float a0 = 0.f, a1 = 0.f, a2 = 0.f, a3 = 0.f, a4 = 0.f, a5 = 0.f, a6 = 0.f, a7 = 0.f;
    float c0 = 0.f, c1 = 0.f, c2 = 0.f, c3 = 0.f, c4 = 0.f, c5 = 0.f, c6 = 0.f, c7 = 0.f;
    int i = s;
    for (; i + 4 <= e; i += 4) {
        int s0 = esrc[i], s1 = esrc[i + 1], s2 = esrc[i + 2], s3 = esrc[i + 3];
        uint2 u0 = h8[(size_t)s0 * 16 + lane];
        uint2 u1 = h8[(size_t)s1 * 16 + lane];
        uint2 u2 = h8[(size_t)s2 * 16 + lane];
        uint2 u3 = h8[(size_t)s3 * 16 + lane];
        float f0 = sc[s0], f1 = sc[s1], f2 = sc[s2], f3 = sc[s3];
        ACCI8(a, u0, f0)
        ACCI8(c, u1, f1)
        ACCI8(a, u2, f2)
        ACCI8(c, u3, f3)
    }
    for (; i < e; ++i) {
        int s0 = esrc[i];
        uint2 u = h8[(size_t)s0 * 16 + lane];
        float f = sc[s0];
        ACCI8(a, u, f)
    }
    a0 += c0; a1 += c1; a2 += c2; a3 += c3;
    a4 += c4; a5 += c5; a6 += c6; a7 += c7;
    float di = dinv[node];
    float4 b0 = ((const float4*)bias)[lane * 2];
    float4 b1 = ((const float4*)bias)[lane * 2 + 1];
    float o0 = fmaf(di, a0, b0.x);
    float o1 = fmaf(di, a1, b0.y);
    float o2 = fmaf(di, a2, b0.z);
    float o3 = fmaf(di, a3, b0.w);
    float o4 = fmaf(di, a4, b1.x);
    float o5 = fmaf(di, a5, b1.y);
    float o6 = fmaf(di, a6, b1.z);
    float o7 = fmaf(di, a7, b1.w);
    if (relu) {
        o0 = fmaxf(o0, 0.f); o1 = fmaxf(o1, 0.f); o2 = fmaxf(o2, 0.f); o3 = fmaxf(o3, 0.f);
        o4 = fmaxf(o4, 0.f); o5 = fmaxf(o5, 0.f); o6 = fmaxf(o6, 0.f); o7 = fmaxf(o7, 0.f);
    }
    ((float4*)out)[(size_t)node * 32 + lane * 2]     = make_float4(o0, o1, o2, o3);
    ((float4*)out)[(size_t)node * 32 + lane * 2 + 1] = make_float4(o4, o5, o6, o7);
}

// ---------------- relation offsets: scan + cursor init ----------------
__global__ void k_roff(const int* __restrict__ rcount, int* __restrict__ roff,
                       int* __restrict__ chunkoff, int* __restrict__ cursor, int nr) {
    if (threadIdx.x == 0 && blockIdx.x == 0) {
        int run = 0, crun = 0;
        for (int r = 0; r < nr; ++r) {
            roff[r] = run; chunkoff[r] = crun; cursor[r] = run;
            run += rcount[r]; crun += (rcount[r] + SC_T - 1) / SC_T;
        }
        roff[nr] = run; chunkoff[nr] = crun;
    }
}

__global__ __launch_bounds__(256) void k_bucket(const int* __restrict__ rel, int* __restrict__ cursor,
                                                int* __restrict__ eidx, int es) {
    __shared__ int lh[16];
    __shared__ int lbase[16];
    int t = threadIdx.x;
    if (t < 16) lh[t] = 0;
    __syncthreads();
    int r[4], lr[4];
#pragma unroll
    for (int i = 0; i < 4; ++i) {
        int e = blockIdx.x * 1024 + i * 256 + t;
        if (e < es) {
            r[i] = rel[e];
            lr[i] = atomicAdd(&lh[r[i]], 1);   // LDS atomic: intra-block rank
        } else r[i] = -1;
    }
    __syncthreads();
    if (t < 16) lbase[t] = lh[t] ? atomicAdd(&cursor[t], lh[t]) : 0;   // reserve range
    __syncthreads();
#pragma unroll
    for (int i = 0; i < 4; ++i)
        if (r[i] >= 0) eidx[lbase[r[i]] + lr[i]] = blockIdx.x * 1024 + i * 256 + t;
}

// ---------------- batched scoring v3: contiguous chunk range per block, W[r] cached ----------------
// R5: SC_T=8 (72.5KB LDS -> 2 blocks/CU). Contiguous chunk ranges: W[r] re-staged only on
// relation change (~3% of steps).
__global__ __launch_bounds__(256) void k_score_r(const float* __restrict__ z, const float* __restrict__ relW,
                                                 const int* __restrict__ eidx, const int* __restrict__ head,
                                                 const int* __restrict__ tail, const int* __restrict__ roff,
                                                 const int* __restrict__ chunkoff, float* __restrict__ out,
                                                 int R_, int cpb) {
    __shared__ __align__(16) float Wl[TD * TD];      // 64 KB
    __shared__ __align__(16) float zhL[SC_T * TD];   // 4 KB
    __shared__ __align__(16) float ztL[SC_T * TD];   // 4 KB
    __shared__ int eids[SC_T];
    __shared__ int co[17], ro[17];
    __shared__ float red[4][SC_T];
    const int t = threadIdx.x;
    if (t < 17 && t <= R_) { co[t] = chunkoff[t]; ro[t] = roff[t]; }
    __syncthreads();
    const int nch = co[R_];                    // total real chunks
    int b = blockIdx.x * cpb;
    const int bend = min(nch, b + cpb);
    int r = 0, rprev = -1;
    for (; b < bend; ++b) {
        while (co[r + 1] <= b) ++r;            // monotone in b; uniform across block
        const int base = ro[r] + (b - co[r]) * SC_T;
        const int nt = min(SC_T, ro[r + 1] - base);
        if (t < SC_T) eids[t] = (t < nt) ? eidx[base + t] : -1;
        const bool newW = (r != rprev);
        rprev = r;
        __syncthreads();                       // eids visible; zhL free (post-compute barrier)
        {   // stage zh/zt: 256 float4, 1 per thread
            int tt = t >> 5, c4 = t & 31;
            float4 vh = make_float4(0.f, 0.f, 0.f, 0.f), vt = vh;
            int e = eids[tt];
            if (e >= 0) {
                vh = ((const float4*)(z + (size_t)head[e] * TD))[c4];
                vt = ((const float4*)(z + (size_t)tail[e] * TD))[c4];
            }
            ((float4*)(zhL + tt * TD))[c4] = vh;
            ((float4*)(ztL + tt * TD))[c4] = vt;
        }
        if (newW) {   // stage W[r]: 4096 float4 (only on relation change)
            const float4* W4 = (const float4*)(relW + (size_t)r * TD * TD);
            float4* Wl4 = (float4*)Wl;
#pragma unroll
            for (int i = 0; i < 16; ++i) Wl4[t + i * 256] = W4[t + i * 256];
        }
        __syncthreads();

        const int c  = (t & 31) * 4;    // cols c..c+3
        const int i0 = (t >> 5) * 16;   // 16-row i segment
        float4 acc[SC_T];
#pragma unroll
        for (int u = 0; u < SC_T; ++u) acc[u] = make_float4(0.f, 0.f, 0.f, 0.f);
#pragma unroll 4
        for (int i = i0; i < i0 + 16; ++i) {
            float4 wv = *(const float4*)&Wl[i * TD + c];
#pragma unroll
            for (int u = 0; u < SC_T; ++u) {
                float h = zhL[u * TD + i];
                acc[u].x = fmaf(h, wv.x, acc[u].x);
                acc[u].y = fmaf(h, wv.y, acc[u].y);
                acc[u].z = fmaf(h, wv.z, acc[u].z);
                acc[u].w = fmaf(h, wv.w, acc[u].w);
            }
        }
        float pth[SC_T];
#pragma unroll
        for (int u = 0; u < SC_T; ++u) {
            float4 z4 = *(const float4*)&ztL[u * TD + c];
            pth[u] = acc[u].x * z4.x + acc[u].y * z4.y + acc[u].z * z4.z + acc[u].w * z4.w;
        }
#pragma unroll
        for (int off = 32; off > 0; off >>= 1)
#pragma unroll
            for (int u = 0; u < SC_T; ++u) pth[u] += __shfl_down(pth[u], off);
        if ((t & 63) == 0) {
            int wv = t >> 6;
#pragma unroll
            for (int u = 0; u < SC_T; ++u) red[wv][u] = pth[u];
        }
        __syncthreads();
        if (t < SC_T) {
            int e = eids[t];
            if (e >= 0) out[e] = red[0][t] + red[1][t] + red[2][t] + red[3][t];
        }
    }
}

extern "C" void kernel_launch(void* const* d_in, const int* in_sizes, int n_in,
                              void* d_out, int out_size, void* d_ws, size_t ws_size,
                              hipStream_t stream) {
    const float* x0   = (const float*)d_in[0];
    const float* W1   = (const float*)d_in[1];
    const float* b1   = (const float*)d_in[2];
    const float* W2   = (const float*)d_in[3];
    const float* b2   = (const float*)d_in[4];
    const float* relW = (const float*)d_in[5];
    const int*   ei   = (const int*)d_in[6];
    const int*   rel  = (const int*)d_in[7];
    const int*   head = (const int*)d_in[8];
    const int*   tail = (const int*)d_in[9];
    float* outp = (float*)d_out;

    const int N_  = in_sizes[0] / TD;
    const int E_  = in_sizes[6] / 2;
    const int ES_ = in_sizes[7];
    const int R_  = in_sizes[5] / (TD * TD);
    const int ntiles64 = (N_ + 63) / 64;
    const int NB    = (N_ + (1 << BKT_SH) - 1) >> BKT_SH;   // <= 1024 for N <= 131072
    const int chunk  = (E_ + NBLK - 1) / NBLK;
    const int rchunk = (ES_ + NBLK - 1) / NBLK;
    const int maxch  = (ES_ + SC_T - 1) / SC_T + R_;        // upper bound on chunk count
    const int sgrid  = maxch < 512 ? maxch : 512;           // 2 blocks/CU
    const int cpb    = (maxch + sgrid - 1) / sgrid;         // chunks per block (contiguous)

    char* p = (char*)d_ws;
    auto alloc = [&](size_t bytes) { char* r = p; p += (bytes + 255) & ~(size_t)255; return r; };
    float*          dinv   = (float*)         alloc((size_t)N_ * 4);
    int*            rowptr = (int*)           alloc(((size_t)N_ + 1) * 4);
    int*            bh     = (int*)           alloc((size_t)NB * NBLK * 4);
    int*            tot    = (int*)           alloc((size_t)NB * 4);
    int*            boff   = (int*)           alloc(((size_t)NB + 1) * 4);
    int*            esrc   = (int*)           alloc((size_t)E_ * 4);
    unsigned short* Wt     = (unsigned short*)alloc((size_t)4 * 16384 * 2);   // W1h,W1l,W2h,W2l
    int*            rcount = (int*)           alloc((size_t)R_ * 4);
    int*            roff   = (int*)           alloc(((size_t)R_ + 1) * 4);
    int*            chkoff = (int*)           alloc(((size_t)R_ + 1) * 4);
    int*            cursor = (int*)           alloc((size_t)R_ * 4);
    int*            eidx   = (int*)           alloc((size_t)ES_ * 4);
    unsigned char*  bufA   = (unsigned char*) alloc((size_t)N_ * TD);         // int8 messages
    float*          sc     = (float*)         alloc((size_t)N_ * 4);          // per-row scales
    float*          bufB   = (float*)         alloc((size_t)N_ * TD * 4);     // f32 conv out
    int*            ebuf   = (int*)bufA;   // alias: dead before first k_gemm writes bufA (E*4 <= N*TD)

    hipMemsetAsync(rcount, 0, (size_t)R_ * 4, stream);

    // atomic-free CSR: hist(+rel histo) -> scanA -> scanB -> scatter -> per-bucket build
    kc_hist <<<NBLK, 256, 0, stream>>>(ei, bh, rel, rcount, E_, ES_, NB, chunk, rchunk);
    kc_scanA<<<NB, 64, 0, stream>>>(bh, tot, NB);
    kc_scanB<<<1, 256, 0, stream>>>(tot, boff, NB, rowptr + N_);
    kc_scat <<<NBLK, 256, 0, stream>>>(ei, bh, boff, ebuf, E_, NB, chunk);
    kc_build<<<NB, 256, 0, stream>>>(ebuf, boff, rowptr, dinv, esrc, N_);

    k_wsplit<<<128, 256, 0, stream>>>(W1, W2, Wt);

    // relation bucketing for scoring
    k_roff  <<<1, 64, 0, stream>>>(rcount, roff, chkoff, cursor, R_);
    k_bucket<<<(ES_ + 1023) / 1024, 256, 0, stream>>>(rel, cursor, eidx, ES_);

    // conv1: bufA,sc = int8(dinv * (x0 @ W1)); bufB = relu(dinv*agg(bufA*sc) + b1)
    k_gemm<<<ntiles64, 256, 0, stream>>>(x0, Wt, Wt + 16384, dinv, bufA, sc, N_);
    k_agg <<<(N_ + 15) / 16, 256, 0, stream>>>(bufA, sc, rowptr, esrc, dinv, b1, bufB, N_, 1);
    // conv2: bufA,sc = int8(dinv * (bufB @ W2)); bufB = dinv*agg(bufA*sc) + b2  (= z)
    k_gemm<<<ntiles64, 256, 0, stream>>>(bufB, Wt + 32768, Wt + 49152, dinv, bufA, sc, N_);
    k_agg <<<(N_ + 15) / 16, 256, 0, stream>>>(bufA, sc, rowptr, esrc, dinv, b2, bufB, N_, 0);

    // scoring: contiguous chunk ranges, W cached across same-relation chunks
    k_score_r<<<sgrid, 256, 0, stream>>>(bufB, relW, eidx, head, tail,
                                         roff, chkoff, outp, R_, cpb);
}